// Round 4
// baseline (1030.429 us; speedup 1.0000x reference)
//
#include <hip/hip_runtime.h>
#include <math.h>

// Problem constants (reference: VOCAB=10000, HID=256, B=64, T=64)
#define VOCABN 10000
#define HIDN   256
#define GATES  1024   // 4*HID
#define BN     64
#define TN     64
#define BT     4096   // B*T
#define NCT    625    // vocab col-tiles of 16 (10000 = 625*16 exactly)

typedef unsigned int   u32;
typedef unsigned short u16;
typedef float v4f __attribute__((ext_vector_type(4)));
typedef short v8s __attribute__((ext_vector_type(8)));

__device__ __forceinline__ float bf2f(u16 u) {
    return __uint_as_float(((u32)u) << 16);
}
__device__ __forceinline__ u16 f2bf(float f) {          // round-to-nearest-even
    u32 u = __float_as_uint(f);
    u += 0x7FFFu + ((u >> 16) & 1u);
    return (u16)(u >> 16);
}
__device__ __forceinline__ float fast_sigmoid(float x) {
    return 1.0f / (1.0f + __expf(-x));
}
__device__ __forceinline__ float fast_tanh(float x) {
    float e = __expf(-2.0f * fabsf(x));
    float t = (1.0f - e) / (1.0f + e);
    return copysignf(t, x);
}

// ---------------------------------------------------------------------------
// Generic fp32 [HIDN][ncols] -> bf16 MFMA B-fragment layout [ct][8 q][64 l][8].
// Fragment (c,q), lane l holds B[k = q*32 + (l>>4)*8 + j][n = c*16 + (l&15)],
// j=0..7, as 16 contiguous bytes -> b_frag load is a single coalesced b128.
// ---------------------------------------------------------------------------
__global__ __launch_bounds__(256) void k_wfrag(
    const float* __restrict__ src,   // [HIDN][ncols]
    u16*         __restrict__ dst,   // [nct][8][64][8]
    int ncols)
{
    __shared__ u16 lt[HIDN][16];
    const int c = blockIdx.x;
    const int t = threadIdx.x;
    const float* s = src + (size_t)t * ncols + c * 16;
    #pragma unroll
    for (int j4 = 0; j4 < 4; ++j4) {
        float4 v = *(const float4*)(s + j4 * 4);
        lt[t][j4*4+0] = f2bf(v.x);
        lt[t][j4*4+1] = f2bf(v.y);
        lt[t][j4*4+2] = f2bf(v.z);
        lt[t][j4*4+3] = f2bf(v.w);
    }
    __syncthreads();
    #pragma unroll
    for (int h = 0; h < 2; ++h) {
        int f = t + h * 256;             // frag id = q*64 + l
        int q = f >> 6, l = f & 63;
        int m = l & 15, kb = q * 32 + ((l >> 4) & 3) * 8;
        u32 w[4];
        #pragma unroll
        for (int j = 0; j < 4; ++j)
            w[j] = (u32)lt[kb + 2*j][m] | ((u32)lt[kb + 2*j + 1][m] << 16);
        *(uint4*)(dst + (((size_t)c * 8 + q) * 64 + l) * 8) =
            make_uint4(w[0], w[1], w[2], w[3]);
    }
}

// ---------------------------------------------------------------------------
// Kernel 1 (MFMA): gates_x = E[idx] @ W_x + b_lstm. 256 blocks x 16 rows.
// ---------------------------------------------------------------------------
__global__ __launch_bounds__(256) void k_xgates(
    const int*   __restrict__ idx,   // [BT]
    const float* __restrict__ E,     // [VOCAB][HIDN]
    const u16*   __restrict__ Wxf,   // [64][8][64][8]
    const float* __restrict__ bl,    // [GATES]
    float*       __restrict__ gx)    // [BT][GATES]
{
    const int r0   = blockIdx.x * 16;
    const int tid  = threadIdx.x;
    const int w    = tid >> 6, lane = tid & 63;
    const int m    = lane & 15, quad = lane >> 4;

    v8s a[8];
    {
        const float* e = E + (size_t)idx[r0 + m] * HIDN + quad * 8;
        #pragma unroll
        for (int q = 0; q < 8; ++q) {
            float4 x0 = *(const float4*)(e + q * 32);
            float4 x1 = *(const float4*)(e + q * 32 + 4);
            uint4 t4 = make_uint4(
                (u32)f2bf(x0.x) | ((u32)f2bf(x0.y) << 16),
                (u32)f2bf(x0.z) | ((u32)f2bf(x0.w) << 16),
                (u32)f2bf(x1.x) | ((u32)f2bf(x1.y) << 16),
                (u32)f2bf(x1.z) | ((u32)f2bf(x1.w) << 16));
            a[q] = *(v8s*)&t4;
        }
    }

    for (int c = w; c < GATES / 16; c += 4) {
        v4f acc = {0.f, 0.f, 0.f, 0.f};
        #pragma unroll
        for (int q = 0; q < 8; ++q) {
            v8s b = *(const v8s*)(Wxf + (((size_t)c * 8 + q) * 64 + lane) * 8);
            acc = __builtin_amdgcn_mfma_f32_16x16x32_bf16(a[q], b, acc, 0, 0, 0);
        }
        const int col = c * 16 + m;
        const float bv = bl[col];
        #pragma unroll
        for (int r = 0; r < 4; ++r)   // D: col=lane&15, row=quad*4+r (m89/m91)
            gx[(size_t)(r0 + quad * 4 + r) * GATES + col] = acc[r] + bv;
    }
}

// ---------------------------------------------------------------------------
// Kernel 2 (persistent MFMA LSTM): 64 blocks = 4 row-groups(16 rows) x 16
// unit-slices(16 units = 64 gate cols). W_h slice LDS-resident in B-frag
// layout. Per step: 8 MFMA/wave (wave = gate type), LDS gate exchange,
// thread-per-(row,unit) cell update, h published to a double-buffered global
// exchange buffer; 16-block barrier per step via device-scope atomics.
// ---------------------------------------------------------------------------
__global__ __launch_bounds__(256) void k_plstm(
    const u16*   __restrict__ Whf,   // [64 ct][8][64][8] h-part frags
    const float* __restrict__ gx,    // [BT][GATES]
    u16*                      Hx,    // [2][BN][HIDN] bf16 exchange
    u16*         __restrict__ Hb,    // [BT][HIDN] bf16 output
    u32*                      bar)   // [4] counters, pre-zeroed per launch
{
    __shared__ uint4 Wl4[4 * 512];       // 32 KB: [ct][8 q][64 l][8] u16
    __shared__ float gl[4][16][16];      // 4 KB gate exchange

    const int tid  = threadIdx.x;
    const int rg   = blockIdx.x >> 4;    // row group: batch rows rg*16..+15
    const int ns   = blockIdx.x & 15;    // unit slice: units ns*16..+15
    const int u0   = ns * 16;
    const int w    = tid >> 6;           // wave = gate type (i,j,f,o)
    const int lane = tid & 63;
    const int m    = lane & 15, kq = lane >> 4;

    // --- load W_h slice: tiles c = w'*16 + ns, 8 KB contiguous each ---
    {
        const uint4* src = (const uint4*)Whf;
        #pragma unroll
        for (int i = 0; i < 8; ++i) {
            int e  = tid + i * 256;          // [0, 2048)
            int ct = e >> 9, off = e & 511;  // 512 uint4 per tile
            Wl4[e] = src[(size_t)(ct * 16 + ns) * 512 + off];
        }
    }
    // zero gate-exchange so t=0 reads 0 for the h@W_h term
    {
        float* g0 = (float*)gl;
        #pragma unroll
        for (int j = 0; j < 4; ++j) g0[tid * 4 + j] = 0.0f;
    }
    __syncthreads();

    const u16* Wl = (const u16*)Wl4;

    // thread-phase identity: (row r, unit u)
    const int r = tid >> 4, u = tid & 15;
    const int b = rg * 16 + r;                       // batch row
    const float* gxp = gx + (size_t)b * TN * GATES + u0 + u;
    u16* hbp = Hb + (size_t)b * TN * HIDN + u0 + u;
    const int hxw = b * HIDN + u0 + u;               // Hx write offset (in-buf)
    const int aoff = (rg * 16 + m) * HIDN + kq * 8;  // a-frag lane offset

    float cst = 0.0f;
    float4 gxr;
    gxr.x = gxp[0]; gxr.y = gxp[256]; gxr.z = gxp[512]; gxr.w = gxp[768];

    for (int t = 0; t < TN; ++t) {
        // prefetch next step's x-gates early (hide HBM latency behind MFMA)
        float4 gxn = gxr;
        if (t + 1 < TN) {
            const float* p = gxp + (size_t)(t + 1) * GATES;
            gxn.x = p[0]; gxn.y = p[256]; gxn.z = p[512]; gxn.w = p[768];
        }

        if (t > 0) {
            const u16* hsrc = Hx + (t & 1) * (BN * HIDN) + aoff;
            v4f acc = {0.f, 0.f, 0.f, 0.f};
            #pragma unroll
            for (int q = 0; q < 8; ++q) {
                v8s a = *(const v8s*)(hsrc + q * 32);
                v8s bf = *(const v8s*)(Wl + ((w * 8 + q) * 64 + lane) * 8);
                acc = __builtin_amdgcn_mfma_f32_16x16x32_bf16(a, bf, acc, 0, 0, 0);
            }
            #pragma unroll
            for (int rr = 0; rr < 4; ++rr)   // row = kq*4+rr, col(unit) = m
                gl[w][kq * 4 + rr][m] = acc[rr];
        }
        __syncthreads();

        {   // cell update for (r, u); c stays in a register
            float ai = gl[0][r][u] + gxr.x;
            float aj = gl[1][r][u] + gxr.y;
            float af = gl[2][r][u] + gxr.z;
            float ao = gl[3][r][u] + gxr.w;
            float ig = fast_sigmoid(ai);
            float fg = fast_sigmoid(af + 1.0f);      // forget_bias = 1.0
            float og = fast_sigmoid(ao);
            float jt = fast_tanh(aj);
            cst = fg * cst + ig * jt;
            float hn = og * fast_tanh(cst);
            u16 hv = f2bf(hn);
            Hx[(((t & 1) ^ 1) * (BN * HIDN)) + hxw] = hv;
            hbp[(size_t)t * HIDN] = hv;
        }

        if (t + 1 < TN) {
            __threadfence();                 // release h stores (device scope)
            __syncthreads();                 // whole block published
            if (tid == 0) {
                atomicAdd(&bar[rg], 1u);
                u32 tgt = (u32)(t + 1) * 16u;
                while (__hip_atomic_load(&bar[rg], __ATOMIC_ACQUIRE,
                                         __HIP_MEMORY_SCOPE_AGENT) < tgt) { }
            }
            __syncthreads();
            __threadfence();                 // acquire: fresh h for next step
        }
        gxr = gxn;
    }
}

// ---------------------------------------------------------------------------
// Kernel 3 (MFMA): sum-of-exp over vocab (no running max: |logit| small, exp
// never overflows fp32). 256 blocks = 128 row-groups x 2 vocab halves.
// ---------------------------------------------------------------------------
__global__ __launch_bounds__(256) void k_dense(
    const u16*   __restrict__ Hb,    // [BT][HIDN] bf16
    const u16*   __restrict__ Wf,    // [625][8][64][8]
    const float* __restrict__ bd,    // [VOCAB]
    float*       __restrict__ S)     // [2][BT] partial sumexp
{
    __shared__ float Sl[32];
    const int rg  = blockIdx.x >> 1, hv = blockIdx.x & 1;
    const int r0  = rg * 32;
    const int tid = threadIdx.x;
    const int w   = tid >> 6, lane = tid & 63;
    const int m   = lane & 15, quad = lane >> 4;

    if (tid < 32) Sl[tid] = 0.0f;

    v8s a[2][8];
    #pragma unroll
    for (int rt = 0; rt < 2; ++rt) {
        const u16* hrow = Hb + (size_t)(r0 + rt * 16 + m) * HIDN + quad * 8;
        #pragma unroll
        for (int q = 0; q < 8; ++q)
            a[rt][q] = *(const v8s*)(hrow + q * 32);
    }
    __syncthreads();

    float s[2][4] = {{0.f,0.f,0.f,0.f},{0.f,0.f,0.f,0.f}};
    const int cbeg = hv ? 313 : 0;
    const int cend = hv ? NCT : 313;
    for (int c = cbeg + w; c < cend; c += 4) {
        v4f acc0 = {0.f,0.f,0.f,0.f};
        v4f acc1 = {0.f,0.f,0.f,0.f};
        #pragma unroll
        for (int q = 0; q < 8; ++q) {
            v8s bq = *(const v8s*)(Wf + (((size_t)c * 8 + q) * 64 + lane) * 8);
            acc0 = __builtin_amdgcn_mfma_f32_16x16x32_bf16(a[0][q], bq, acc0, 0, 0, 0);
            acc1 = __builtin_amdgcn_mfma_f32_16x16x32_bf16(a[1][q], bq, acc1, 0, 0, 0);
        }
        float bv = bd[c * 16 + m];
        #pragma unroll
        for (int r = 0; r < 4; ++r) {
            s[0][r] += __expf(acc0[r] + bv);
            s[1][r] += __expf(acc1[r] + bv);
        }
    }

    #pragma unroll
    for (int rt = 0; rt < 2; ++rt)
        #pragma unroll
        for (int r = 0; r < 4; ++r)
            atomicAdd(&Sl[rt * 16 + quad * 4 + r], s[rt][r]);
    __syncthreads();
    if (tid < 32) S[(size_t)hv * BT + r0 + tid] = Sl[tid];
}

// ---------------------------------------------------------------------------
// Kernel 4: target logit per row (direct dot from bf16 frags). 32 thr/row.
// ---------------------------------------------------------------------------
__global__ __launch_bounds__(256) void k_target(
    const u16*   __restrict__ Hb,
    const u16*   __restrict__ Wf,
    const float* __restrict__ bd,
    const int*   __restrict__ tgt,
    float*       __restrict__ tl)    // [BT]
{
    const int tid = threadIdx.x;
    const int row = blockIdx.x * 8 + (tid >> 5);
    const int t   = tid & 31;
    const int q   = t >> 2, lq = t & 3;
    const int v   = tgt[row];
    const int c   = v >> 4, vm = v & 15;
    const int kb  = q * 32 + lq * 8;

    v8s h  = *(const v8s*)(Hb + (size_t)row * HIDN + kb);
    v8s wv = *(const v8s*)(Wf + (((size_t)c * 8 + q) * 64 + lq * 16 + vm) * 8);
    float acc = 0.0f;
    #pragma unroll
    for (int j = 0; j < 8; ++j)
        acc = fmaf(bf2f((u16)h[j]), bf2f((u16)wv[j]), acc);
    #pragma unroll
    for (int off = 16; off >= 1; off >>= 1)
        acc += __shfl_down(acc, off, 32);
    if (t == 0) tl[row] = acc + bd[v];
}

// ---------------------------------------------------------------------------
// Kernel 5: ppl = exp(log(sumexp) - target_logit)
// ---------------------------------------------------------------------------
__global__ __launch_bounds__(256) void k_final(
    const float* __restrict__ S,     // [2][BT]
    const float* __restrict__ tl,    // [BT]
    float*       __restrict__ out)   // [BT]
{
    int i = blockIdx.x * 256 + threadIdx.x;
    out[i] = __expf(__logf(S[i] + S[BT + i]) - tl[i]);
}

// ---------------------------------------------------------------------------
extern "C" void kernel_launch(void* const* d_in, const int* in_sizes, int n_in,
                              void* d_out, int out_size, void* d_ws, size_t ws_size,
                              hipStream_t stream) {
    const int*   input   = (const int*)  d_in[0];   // [B,T]
    const int*   targets = (const int*)  d_in[1];   // [B,T]
    const float* E       = (const float*)d_in[2];   // [VOCAB,HID]
    const float* W_lstm  = (const float*)d_in[3];   // [2H,4H]
    const float* b_lstm  = (const float*)d_in[4];   // [4H]
    const float* W_dense = (const float*)d_in[5];   // [HID,VOCAB]
    const float* b_dense = (const float*)d_in[6];   // [VOCAB]
    float* out = (float*)d_out;                     // [B,T] perplexity

    // Workspace (< 20 MB):
    //  [0,16M):            gx fp32 [BT][GATES]; reused for Wf (5.12 MB) after
    //                      k_plstm consumes gx — stream-ordered, no overlap.
    //  [16M,18M):          Hb bf16 [BT][HIDN]
    //  [18M,+512K):        Whf bf16 [64][8][64][8] (h-part frags)
    //  [18.5M,+512K):      Wxf bf16 [64][8][64][8] (x-part frags)
    //  [19M,+64K):         Hx bf16 [2][BN][HIDN] exchange
    //  [19M+64K,+32K):     S fp32 [2][BT]
    //  [19M+96K,+16K):     tl fp32 [BT]
    //  [19M+112K,+256B):   bar u32 [4]
    char* ws = (char*)d_ws;
    float* gx  = (float*)ws;
    u16*   Wf  = (u16*)ws;
    u16*   Hb  = (u16*)(ws + ((size_t)16 << 20));
    u16*   Whf = (u16*)(ws + ((size_t)18 << 20));
    u16*   Wxf = (u16*)(ws + ((size_t)18 << 20) + ((size_t)512 << 10));
    u16*   Hx  = (u16*)(ws + ((size_t)19 << 20));
    float* S   = (float*)(ws + ((size_t)19 << 20) + ((size_t)64 << 10));
    float* tl  = (float*)(ws + ((size_t)19 << 20) + ((size_t)96 << 10));
    u32*   bar = (u32*)  (ws + ((size_t)19 << 20) + ((size_t)112 << 10));

    hipMemsetAsync(bar, 0, 256, stream);
    k_wfrag <<<64,      256, 0, stream>>>(W_lstm,                      Wxf, GATES);
    k_wfrag <<<64,      256, 0, stream>>>(W_lstm + (size_t)HIDN*GATES, Whf, GATES);
    k_xgates<<<BT / 16, 256, 0, stream>>>(input, E, Wxf, b_lstm, gx);
    k_plstm <<<64,      256, 0, stream>>>(Whf, gx, Hx, Hb, bar);
    k_wfrag <<<NCT,     256, 0, stream>>>(W_dense, Wf, VOCABN);   // reuses gx
    k_dense <<<256,     256, 0, stream>>>(Hb, Wf, b_dense, S);
    k_target<<<BT / 8,  256, 0, stream>>>(Hb, Wf, b_dense, targets, tl);
    k_final <<<BT / 256,256, 0, stream>>>(S, tl, out);
}

// Round 5
// 423.449 us; speedup vs baseline: 2.4334x; 2.4334x over previous
//
#include <hip/hip_runtime.h>
#include <math.h>

// Problem constants (reference: VOCAB=10000, HID=256, B=64, T=64)
#define VOCABN 10000
#define HIDN   256
#define GATES  1024   // 4*HID
#define BN     64
#define TN     64
#define BT     4096   // B*T
#define NCT    625    // vocab col-tiles of 16 (10000 = 625*16 exactly)

typedef unsigned int       u32;
typedef unsigned short     u16;
typedef unsigned long long u64;
typedef float v4f __attribute__((ext_vector_type(4)));
typedef short v8s __attribute__((ext_vector_type(8)));

__device__ __forceinline__ float bf2f(u16 u) {
    return __uint_as_float(((u32)u) << 16);
}
__device__ __forceinline__ u16 f2bf(float f) {          // round-to-nearest-even
    u32 u = __float_as_uint(f);
    u += 0x7FFFu + ((u >> 16) & 1u);
    return (u16)(u >> 16);
}
__device__ __forceinline__ float fast_sigmoid(float x) {
    return 1.0f / (1.0f + __expf(-x));
}
__device__ __forceinline__ float fast_tanh(float x) {
    float e = __expf(-2.0f * fabsf(x));
    float t = (1.0f - e) / (1.0f + e);
    return copysignf(t, x);
}

// ---------------------------------------------------------------------------
// Generic fp32 [HIDN][ncols] -> bf16 MFMA B-fragment layout [ct][8 q][64 l][8].
// Fragment (c,q), lane l holds B[k = q*32 + (l>>4)*8 + j][n = c*16 + (l&15)],
// j=0..7, as 16 contiguous bytes -> b_frag load is a single coalesced b128.
// ---------------------------------------------------------------------------
__global__ __launch_bounds__(256) void k_wfrag(
    const float* __restrict__ src,   // [HIDN][ncols]
    u16*         __restrict__ dst,   // [nct][8][64][8]
    int ncols)
{
    __shared__ u16 lt[HIDN][16];
    const int c = blockIdx.x;
    const int t = threadIdx.x;
    const float* s = src + (size_t)t * ncols + c * 16;
    #pragma unroll
    for (int j4 = 0; j4 < 4; ++j4) {
        float4 v = *(const float4*)(s + j4 * 4);
        lt[t][j4*4+0] = f2bf(v.x);
        lt[t][j4*4+1] = f2bf(v.y);
        lt[t][j4*4+2] = f2bf(v.z);
        lt[t][j4*4+3] = f2bf(v.w);
    }
    __syncthreads();
    #pragma unroll
    for (int h = 0; h < 2; ++h) {
        int f = t + h * 256;             // frag id = q*64 + l
        int q = f >> 6, l = f & 63;
        int m = l & 15, kb = q * 32 + ((l >> 4) & 3) * 8;
        u32 w[4];
        #pragma unroll
        for (int j = 0; j < 4; ++j)
            w[j] = (u32)lt[kb + 2*j][m] | ((u32)lt[kb + 2*j + 1][m] << 16);
        *(uint4*)(dst + (((size_t)c * 8 + q) * 64 + l) * 8) =
            make_uint4(w[0], w[1], w[2], w[3]);
    }
}

// ---------------------------------------------------------------------------
// Kernel 1 (MFMA): gates_x = E[idx] @ W_x + b_lstm. 256 blocks x 16 rows.
// ---------------------------------------------------------------------------
__global__ __launch_bounds__(256) void k_xgates(
    const int*   __restrict__ idx,   // [BT]
    const float* __restrict__ E,     // [VOCAB][HIDN]
    const u16*   __restrict__ Wxf,   // [64][8][64][8]
    const float* __restrict__ bl,    // [GATES]
    float*       __restrict__ gx)    // [BT][GATES]
{
    const int r0   = blockIdx.x * 16;
    const int tid  = threadIdx.x;
    const int w    = tid >> 6, lane = tid & 63;
    const int m    = lane & 15, quad = lane >> 4;

    v8s a[8];
    {
        const float* e = E + (size_t)idx[r0 + m] * HIDN + quad * 8;
        #pragma unroll
        for (int q = 0; q < 8; ++q) {
            float4 x0 = *(const float4*)(e + q * 32);
            float4 x1 = *(const float4*)(e + q * 32 + 4);
            uint4 t4 = make_uint4(
                (u32)f2bf(x0.x) | ((u32)f2bf(x0.y) << 16),
                (u32)f2bf(x0.z) | ((u32)f2bf(x0.w) << 16),
                (u32)f2bf(x1.x) | ((u32)f2bf(x1.y) << 16),
                (u32)f2bf(x1.z) | ((u32)f2bf(x1.w) << 16));
            a[q] = *(v8s*)&t4;
        }
    }

    for (int c = w; c < GATES / 16; c += 4) {
        v4f acc = {0.f, 0.f, 0.f, 0.f};
        #pragma unroll
        for (int q = 0; q < 8; ++q) {
            v8s b = *(const v8s*)(Wxf + (((size_t)c * 8 + q) * 64 + lane) * 8);
            acc = __builtin_amdgcn_mfma_f32_16x16x32_bf16(a[q], b, acc, 0, 0, 0);
        }
        const int col = c * 16 + m;
        const float bv = bl[col];
        #pragma unroll
        for (int r = 0; r < 4; ++r)   // D: col=lane&15, row=quad*4+r (m89/m91)
            gx[(size_t)(r0 + quad * 4 + r) * GATES + col] = acc[r] + bv;
    }
}

// ---------------------------------------------------------------------------
// Kernel 2 (persistent MFMA LSTM): 64 blocks = 4 row-groups(16 rows) x 16
// unit-slices. W_h slice LDS-resident. Cross-block h-exchange goes through
// the LLC ONLY via relaxed agent-scope atomic u64 ops (global_* sc0 sc1 —
// no buffer_inv / buffer_wbl2, which is what killed the R4 version: device
// threadfence + acquire spins walked the 4MB L2 every step ~13us/step).
// Writer ordering: __syncthreads() drains each wave's stores (vmcnt(0)
// before s_barrier) before tid0 bumps the relaxed LLC counter.
// ---------------------------------------------------------------------------
__global__ __launch_bounds__(256) void k_plstm(
    const u16*   __restrict__ Whf,   // [64 ct][8][64][8] h-part frags
    const float* __restrict__ gx,    // [BT][GATES]
    u16*                      Hx,    // [2][BN][HIDN] bf16 exchange (LLC)
    u16*         __restrict__ Hb,    // [BT][HIDN] bf16 output
    u32*                      bar)   // counters (stride 64), zeroed per launch
{
    __shared__ uint4 Wl4[4 * 512];       // 32 KB: [ct][8 q][64 l][8] u16
    __shared__ float gl[4][16][16];      // 4 KB gate exchange

    const int tid  = threadIdx.x;
    const int rg   = blockIdx.x >> 4;    // row group: batch rows rg*16..+15
    const int ns   = blockIdx.x & 15;    // unit slice: units ns*16..+15
    const int u0   = ns * 16;
    const int w    = tid >> 6;           // wave = gate type (i,j,f,o)
    const int lane = tid & 63;
    const int m    = lane & 15, kq = lane >> 4;

    // --- load W_h slice: tiles c = w'*16 + ns, 8 KB contiguous each ---
    {
        const uint4* src = (const uint4*)Whf;
        #pragma unroll
        for (int i = 0; i < 8; ++i) {
            int e  = tid + i * 256;          // [0, 2048)
            int ct = e >> 9, off = e & 511;  // 512 uint4 per tile
            Wl4[e] = src[(size_t)(ct * 16 + ns) * 512 + off];
        }
    }
    {   // zero gate-exchange so t=0 reads 0 for the h@W_h term
        float* g0 = (float*)gl;
        #pragma unroll
        for (int j = 0; j < 4; ++j) g0[tid * 4 + j] = 0.0f;
    }
    __syncthreads();

    const u16* Wl = (const u16*)Wl4;

    // thread-phase identity: (row r, unit u)
    const int r = tid >> 4, u = tid & 15;
    const int b = rg * 16 + r;                       // batch row
    const float* gxp = gx + (size_t)b * TN * GATES + u0 + u;
    u16* hbp = Hb + (size_t)b * TN * HIDN + u0 + u;
    const int hxw = b * HIDN + u0 + u;               // Hx elem offset (in-buf)
    const int aoff = (rg * 16 + m) * HIDN + kq * 8;  // a-frag elem offset (x8)

    float cst = 0.0f;
    float4 gxr;
    gxr.x = gxp[0]; gxr.y = gxp[256]; gxr.z = gxp[512]; gxr.w = gxp[768];

    for (int t = 0; t < TN; ++t) {
        // prefetch next step's x-gates early (hide HBM latency behind MFMA)
        float4 gxn = gxr;
        if (t + 1 < TN) {
            const float* p = gxp + (size_t)(t + 1) * GATES;
            gxn.x = p[0]; gxn.y = p[256]; gxn.z = p[512]; gxn.w = p[768];
        }

        if (t > 0) {
            // a-frags from LLC: relaxed agent u64 atomic loads (sc0 sc1)
            const u64* hsrc = (const u64*)(Hx + (t & 1) * (BN * HIDN) + aoff);
            v4f acc = {0.f, 0.f, 0.f, 0.f};
            #pragma unroll
            for (int q = 0; q < 8; ++q) {
                union { u64 d[2]; v8s v; } av;
                av.d[0] = __hip_atomic_load(hsrc + q * 8,     __ATOMIC_RELAXED,
                                            __HIP_MEMORY_SCOPE_AGENT);
                av.d[1] = __hip_atomic_load(hsrc + q * 8 + 1, __ATOMIC_RELAXED,
                                            __HIP_MEMORY_SCOPE_AGENT);
                v8s bf = *(const v8s*)(Wl + ((w * 8 + q) * 64 + lane) * 8);
                acc = __builtin_amdgcn_mfma_f32_16x16x32_bf16(av.v, bf, acc, 0, 0, 0);
            }
            #pragma unroll
            for (int rr = 0; rr < 4; ++rr)   // row = kq*4+rr, col(unit) = m
                gl[w][kq * 4 + rr][m] = acc[rr];
        }
        __syncthreads();

        {   // cell update for (r, u); c stays in a register
            float ai = gl[0][r][u] + gxr.x;
            float aj = gl[1][r][u] + gxr.y;
            float af = gl[2][r][u] + gxr.z;
            float ao = gl[3][r][u] + gxr.w;
            float ig = fast_sigmoid(ai);
            float fg = fast_sigmoid(af + 1.0f);      // forget_bias = 1.0
            float og = fast_sigmoid(ao);
            float jt = fast_tanh(aj);
            cst = fg * cst + ig * jt;
            float hn = og * fast_tanh(cst);
            u32 hv = f2bf(hn);
            hbp[(size_t)t * HIDN] = (u16)hv;

            if (t + 1 < TN) {
                // pack 4 consecutive units (same row, lanes tid..tid+3) into
                // one u64 and publish via relaxed agent atomic store -> LLC
                u32 p1 = __shfl_down(hv, 1);
                u32 p2 = __shfl_down(hv, 2);
                u32 p3 = __shfl_down(hv, 3);
                if ((tid & 3) == 0) {
                    u64 pk = (u64)(hv | (p1 << 16))
                           | ((u64)(p2 | (p3 << 16)) << 32);
                    u64* dst = (u64*)(Hx + (((t & 1) ^ 1) * (BN * HIDN)) + hxw);
                    __hip_atomic_store(dst, pk, __ATOMIC_RELAXED,
                                       __HIP_MEMORY_SCOPE_AGENT);
                }
            }
        }

        if (t + 1 < TN) {
            __syncthreads();   // per-wave vmcnt(0) before s_barrier: all
                               // publish stores have reached the LLC
            if (tid == 0) {
                __hip_atomic_fetch_add(&bar[rg * 64], 1u, __ATOMIC_RELAXED,
                                       __HIP_MEMORY_SCOPE_AGENT);
                u32 tgt = (u32)(t + 1) * 16u;
                while (__hip_atomic_load(&bar[rg * 64], __ATOMIC_RELAXED,
                                         __HIP_MEMORY_SCOPE_AGENT) < tgt)
                    __builtin_amdgcn_s_sleep(1);
            }
            __syncthreads();   // broadcast release; also orders next gl writes
        }
        gxr = gxn;
    }
}

// ---------------------------------------------------------------------------
// Kernel 3 (MFMA): sum-of-exp over vocab (no running max: |logit| small, exp
// never overflows fp32). 256 blocks = 128 row-groups x 2 vocab halves.
// ---------------------------------------------------------------------------
__global__ __launch_bounds__(256) void k_dense(
    const u16*   __restrict__ Hb,    // [BT][HIDN] bf16
    const u16*   __restrict__ Wf,    // [625][8][64][8]
    const float* __restrict__ bd,    // [VOCAB]
    float*       __restrict__ S)     // [2][BT] partial sumexp
{
    __shared__ float Sl[32];
    const int rg  = blockIdx.x >> 1, hv = blockIdx.x & 1;
    const int r0  = rg * 32;
    const int tid = threadIdx.x;
    const int w   = tid >> 6, lane = tid & 63;
    const int m   = lane & 15, quad = lane >> 4;

    if (tid < 32) Sl[tid] = 0.0f;

    v8s a[2][8];
    #pragma unroll
    for (int rt = 0; rt < 2; ++rt) {
        const u16* hrow = Hb + (size_t)(r0 + rt * 16 + m) * HIDN + quad * 8;
        #pragma unroll
        for (int q = 0; q < 8; ++q)
            a[rt][q] = *(const v8s*)(hrow + q * 32);
    }
    __syncthreads();

    float s[2][4] = {{0.f,0.f,0.f,0.f},{0.f,0.f,0.f,0.f}};
    const int cbeg = hv ? 313 : 0;
    const int cend = hv ? NCT : 313;
    for (int c = cbeg + w; c < cend; c += 4) {
        v4f acc0 = {0.f,0.f,0.f,0.f};
        v4f acc1 = {0.f,0.f,0.f,0.f};
        #pragma unroll
        for (int q = 0; q < 8; ++q) {
            v8s bq = *(const v8s*)(Wf + (((size_t)c * 8 + q) * 64 + lane) * 8);
            acc0 = __builtin_amdgcn_mfma_f32_16x16x32_bf16(a[0][q], bq, acc0, 0, 0, 0);
            acc1 = __builtin_amdgcn_mfma_f32_16x16x32_bf16(a[1][q], bq, acc1, 0, 0, 0);
        }
        float bv = bd[c * 16 + m];
        #pragma unroll
        for (int r = 0; r < 4; ++r) {
            s[0][r] += __expf(acc0[r] + bv);
            s[1][r] += __expf(acc1[r] + bv);
        }
    }

    #pragma unroll
    for (int rt = 0; rt < 2; ++rt)
        #pragma unroll
        for (int r = 0; r < 4; ++r)
            atomicAdd(&Sl[rt * 16 + quad * 4 + r], s[rt][r]);
    __syncthreads();
    if (tid < 32) S[(size_t)hv * BT + r0 + tid] = Sl[tid];
}

// ---------------------------------------------------------------------------
// Kernel 4: target logit per row (direct dot from bf16 frags). 32 thr/row.
// ---------------------------------------------------------------------------
__global__ __launch_bounds__(256) void k_target(
    const u16*   __restrict__ Hb,
    const u16*   __restrict__ Wf,
    const float* __restrict__ bd,
    const int*   __restrict__ tgt,
    float*       __restrict__ tl)    // [BT]
{
    const int tid = threadIdx.x;
    const int row = blockIdx.x * 8 + (tid >> 5);
    const int t   = tid & 31;
    const int q   = t >> 2, lq = t & 3;
    const int v   = tgt[row];
    const int c   = v >> 4, vm = v & 15;
    const int kb  = q * 32 + lq * 8;

    v8s h  = *(const v8s*)(Hb + (size_t)row * HIDN + kb);
    v8s wv = *(const v8s*)(Wf + (((size_t)c * 8 + q) * 64 + lq * 16 + vm) * 8);
    float acc = 0.0f;
    #pragma unroll
    for (int j = 0; j < 8; ++j)
        acc = fmaf(bf2f((u16)h[j]), bf2f((u16)wv[j]), acc);
    #pragma unroll
    for (int off = 16; off >= 1; off >>= 1)
        acc += __shfl_down(acc, off, 32);
    if (t == 0) tl[row] = acc + bd[v];
}

// ---------------------------------------------------------------------------
// Kernel 5: ppl = exp(log(sumexp) - target_logit)
// ---------------------------------------------------------------------------
__global__ __launch_bounds__(256) void k_final(
    const float* __restrict__ S,     // [2][BT]
    const float* __restrict__ tl,    // [BT]
    float*       __restrict__ out)   // [BT]
{
    int i = blockIdx.x * 256 + threadIdx.x;
    out[i] = __expf(__logf(S[i] + S[BT + i]) - tl[i]);
}

// ---------------------------------------------------------------------------
extern "C" void kernel_launch(void* const* d_in, const int* in_sizes, int n_in,
                              void* d_out, int out_size, void* d_ws, size_t ws_size,
                              hipStream_t stream) {
    const int*   input   = (const int*)  d_in[0];   // [B,T]
    const int*   targets = (const int*)  d_in[1];   // [B,T]
    const float* E       = (const float*)d_in[2];   // [VOCAB,HID]
    const float* W_lstm  = (const float*)d_in[3];   // [2H,4H]
    const float* b_lstm  = (const float*)d_in[4];   // [4H]
    const float* W_dense = (const float*)d_in[5];   // [HID,VOCAB]
    const float* b_dense = (const float*)d_in[6];   // [VOCAB]
    float* out = (float*)d_out;                     // [B,T] perplexity

    // Workspace (< 20 MB):
    //  [0,16M):            gx fp32 [BT][GATES]; reused for Wf (5.12 MB) after
    //                      k_plstm consumes gx — stream-ordered, no overlap.
    //  [16M,18M):          Hb bf16 [BT][HIDN]
    //  [18M,+512K):        Whf bf16 [64][8][64][8] (h-part frags)
    //  [18.5M,+512K):      Wxf bf16 [64][8][64][8] (x-part frags)
    //  [19M,+64K):         Hx bf16 [2][BN][HIDN] exchange
    //  [19M+64K,+32K):     S fp32 [2][BT]
    //  [19M+96K,+16K):     tl fp32 [BT]
    //  [19M+112K,+1K):     bar u32 [4*64] (256B-strided counters)
    char* ws = (char*)d_ws;
    float* gx  = (float*)ws;
    u16*   Wf  = (u16*)ws;
    u16*   Hb  = (u16*)(ws + ((size_t)16 << 20));
    u16*   Whf = (u16*)(ws + ((size_t)18 << 20));
    u16*   Wxf = (u16*)(ws + ((size_t)18 << 20) + ((size_t)512 << 10));
    u16*   Hx  = (u16*)(ws + ((size_t)19 << 20));
    float* S   = (float*)(ws + ((size_t)19 << 20) + ((size_t)64 << 10));
    float* tl  = (float*)(ws + ((size_t)19 << 20) + ((size_t)96 << 10));
    u32*   bar = (u32*)  (ws + ((size_t)19 << 20) + ((size_t)112 << 10));

    hipMemsetAsync(bar, 0, 1024, stream);
    k_wfrag <<<64,      256, 0, stream>>>(W_lstm,                      Wxf, GATES);
    k_wfrag <<<64,      256, 0, stream>>>(W_lstm + (size_t)HIDN*GATES, Whf, GATES);
    k_xgates<<<BT / 16, 256, 0, stream>>>(input, E, Wxf, b_lstm, gx);
    k_plstm <<<64,      256, 0, stream>>>(Whf, gx, Hx, Hb, bar);
    k_wfrag <<<NCT,     256, 0, stream>>>(W_dense, Wf, VOCABN);   // reuses gx
    k_dense <<<256,     256, 0, stream>>>(Hb, Wf, b_dense, S);
    k_target<<<BT / 8,  256, 0, stream>>>(Hb, Wf, b_dense, targets, tl);
    k_final <<<BT / 256,256, 0, stream>>>(S, tl, out);
}